// Round 1
// baseline (125.278 us; speedup 1.0000x reference)
//
#include <hip/hip_runtime.h>

#define HW   3136   // 56*56
#define HW4  784    // float4 per (b,c) row
#define C    512
#define B    32
#define M    8
#define ROWS (B * C)  // 16384

// One wave (64 lanes) per (b,c) row: vectorized float4 loads + shuffle reduce.
__global__ __launch_bounds__(256) void se_mean_kernel(const float* __restrict__ x,
                                                      float* __restrict__ y) {
    const int wave = threadIdx.x >> 6;
    const int lane = threadIdx.x & 63;
    const int row  = blockIdx.x * 4 + wave;   // [0, 16384)
    const float4* xr = reinterpret_cast<const float4*>(x) + (size_t)row * HW4;

    float s = 0.f;
    for (int i = lane; i < HW4; i += 64) {
        float4 v = xr[i];
        s += v.x + v.y + v.z + v.w;
    }
    #pragma unroll
    for (int off = 32; off; off >>= 1) s += __shfl_down(s, off, 64);
    if (lane == 0) y[row] = s * (1.0f / HW);
}

// One block, 256 threads: thread t = (b, m) computes gate[b][m].
__global__ __launch_bounds__(256) void se_gate_kernel(const float* __restrict__ y,
                                                      const float* __restrict__ Wt,
                                                      const float* __restrict__ bias,
                                                      float* __restrict__ gate) {
    const int t = threadIdx.x;       // 0..255
    const int b = t >> 3;            // 0..31
    const int m = t & 7;             // 0..7
    const float* yr = y + b * C;
    const float* wr = Wt + m * C;
    float s = 0.f;
    for (int c = 0; c < C; ++c) s += yr[c] * wr[c];
    s += bias[m];
    s = fmaxf(s, 0.f);               // relu
    s = 1.0f / (1.0f + expf(-s));    // sigmoid
    gate[t] = s;                     // gate[b*8 + m]
}

// One block per (b,c) row: out = x * gate[b][c>>6], float4 R/W.
__global__ __launch_bounds__(256) void se_scale_kernel(const float* __restrict__ x,
                                                       const float* __restrict__ gate,
                                                       float* __restrict__ out) {
    const int row = blockIdx.x;          // [0, 16384)
    const int b   = row >> 9;            // row / 512
    const int c   = row & (C - 1);       // row % 512
    const float g = gate[(b << 3) + (c >> 6)];

    const float4* xr = reinterpret_cast<const float4*>(x)   + (size_t)row * HW4;
    float4*       orow = reinterpret_cast<float4*>(out)     + (size_t)row * HW4;

    for (int i = threadIdx.x; i < HW4; i += 256) {
        float4 v = xr[i];
        v.x *= g; v.y *= g; v.z *= g; v.w *= g;
        orow[i] = v;
    }
}

extern "C" void kernel_launch(void* const* d_in, const int* in_sizes, int n_in,
                              void* d_out, int out_size, void* d_ws, size_t ws_size,
                              hipStream_t stream) {
    const float* x    = (const float*)d_in[0];  // (32,512,56,56)
    const float* Wt   = (const float*)d_in[1];  // (8,512)
    const float* bias = (const float*)d_in[2];  // (8,)
    float* out = (float*)d_out;

    float* y    = (float*)d_ws;                 // 16384 floats = 64 KB
    float* gate = y + ROWS;                     // 256 floats

    se_mean_kernel<<<ROWS / 4, 256, 0, stream>>>(x, y);
    se_gate_kernel<<<1, 256, 0, stream>>>(y, Wt, bias, gate);
    se_scale_kernel<<<ROWS, 256, 0, stream>>>(x, gate, out);
}

// Round 2
// 113.054 us; speedup vs baseline: 1.1081x; 1.1081x over previous
//
#include <hip/hip_runtime.h>

#define HW   3136   // 56*56
#define HW4  784    // float4 per (b,c) row
#define C    512
#define B    32
#define ROWS (B * C)  // 16384

// One wave (64 lanes) per (b,c) row: vectorized float4 loads + shuffle reduce.
__global__ __launch_bounds__(256) void se_mean_kernel(const float* __restrict__ x,
                                                      float* __restrict__ y) {
    const int wave = threadIdx.x >> 6;
    const int lane = threadIdx.x & 63;
    const int row  = blockIdx.x * 4 + wave;   // [0, 16384)
    const float4* xr = reinterpret_cast<const float4*>(x) + (size_t)row * HW4;

    float s = 0.f;
    for (int i = lane; i < HW4; i += 64) {
        float4 v = xr[i];
        s += (v.x + v.y) + (v.z + v.w);
    }
    #pragma unroll
    for (int off = 32; off; off >>= 1) s += __shfl_down(s, off, 64);
    if (lane == 0) y[row] = s * (1.0f / HW);
}

// Fused gate + scale. Block owns 4 consecutive rows; 4 consecutive c starting
// at a multiple of 4 never cross a 64-channel modality boundary, so the whole
// block shares ONE gate value g = sigmoid(relu(y[b,:]·W[m,:] + bias[m])).
// Each wave computes g redundantly (no LDS, no __syncthreads), then scales
// its own row with lane-strided float4 (784 = 12*64 + 16: tiny tail).
__global__ __launch_bounds__(256) void se_scale_kernel(const float* __restrict__ x,
                                                       const float* __restrict__ y,
                                                       const float* __restrict__ W,
                                                       const float* __restrict__ bias,
                                                       float* __restrict__ out) {
    const int row0 = blockIdx.x * 4;
    const int b    = row0 >> 9;             // row0 / 512
    const int m    = (row0 & (C - 1)) >> 6; // modality of all 4 rows
    const int wave = threadIdx.x >> 6;
    const int lane = threadIdx.x & 63;

    // gate: 512-length dot, 8 FMA per lane, full butterfly so every lane has it
    const float* yb = y + b * C;
    const float* wm = W + m * C;
    float s = 0.f;
    #pragma unroll
    for (int i = 0; i < 8; ++i) s = fmaf(yb[lane + 64 * i], wm[lane + 64 * i], s);
    #pragma unroll
    for (int off = 32; off; off >>= 1) s += __shfl_xor(s, off, 64);
    s += bias[m];
    s = fmaxf(s, 0.f);                  // relu
    const float g = 1.0f / (1.0f + expf(-s));  // sigmoid

    const int row = row0 + wave;
    const float4* xr  = reinterpret_cast<const float4*>(x) + (size_t)row * HW4;
    float4*      orow = reinterpret_cast<float4*>(out)     + (size_t)row * HW4;
    for (int i = lane; i < HW4; i += 64) {
        float4 v = xr[i];
        v.x *= g; v.y *= g; v.z *= g; v.w *= g;
        orow[i] = v;
    }
}

extern "C" void kernel_launch(void* const* d_in, const int* in_sizes, int n_in,
                              void* d_out, int out_size, void* d_ws, size_t ws_size,
                              hipStream_t stream) {
    const float* x    = (const float*)d_in[0];  // (32,512,56,56)
    const float* W    = (const float*)d_in[1];  // (8,512)
    const float* bias = (const float*)d_in[2];  // (8,)
    float* out = (float*)d_out;

    float* y = (float*)d_ws;                    // 16384 floats = 64 KB

    se_mean_kernel<<<ROWS / 4, 256, 0, stream>>>(x, y);
    se_scale_kernel<<<ROWS / 4, 256, 0, stream>>>(x, y, W, bias, out);
}

// Round 4
// 94.986 us; speedup vs baseline: 1.3189x; 1.1902x over previous
//
#include <hip/hip_runtime.h>

#define HW   3136   // 56*56
#define HW4  784    // float4 per (b,c) row
#define C    512
#define B    32
#define ROWS (B * C)  // 16384

typedef float floatx4 __attribute__((ext_vector_type(4)));  // native vec for nt builtins

// One wave (64 lanes) per (b,c) row: vectorized float4 loads + shuffle reduce.
__global__ __launch_bounds__(256) void se_mean_kernel(const float* __restrict__ x,
                                                      float* __restrict__ y) {
    const int wave = threadIdx.x >> 6;
    const int lane = threadIdx.x & 63;
    const int row  = blockIdx.x * 4 + wave;   // [0, 16384)
    const floatx4* xr = reinterpret_cast<const floatx4*>(x) + (size_t)row * HW4;

    float s = 0.f;
    for (int i = lane; i < HW4; i += 64) {
        floatx4 v = xr[i];
        s += (v.x + v.y) + (v.z + v.w);
    }
    #pragma unroll
    for (int off = 32; off; off >>= 1) s += __shfl_down(s, off, 64);
    if (lane == 0) y[row] = s * (1.0f / HW);
}

// Fused gate + scale. Block owns 4 consecutive rows (same b, same modality m).
// Each wave computes the shared gate redundantly (no LDS / no barrier), then
// scales its row. Rows are processed in REVERSE so the L3-hottest tail of x
// (just streamed by the mean pass) is read first; out is stored non-temporal
// so the write stream doesn't evict x from Infinity Cache.
__global__ __launch_bounds__(256) void se_scale_kernel(const float* __restrict__ x,
                                                       const float* __restrict__ y,
                                                       const float* __restrict__ W,
                                                       const float* __restrict__ bias,
                                                       float* __restrict__ out) {
    const int row0 = (gridDim.x - 1 - blockIdx.x) * 4;  // reverse order
    const int b    = row0 >> 9;             // row0 / 512
    const int m    = (row0 & (C - 1)) >> 6; // modality of all 4 rows
    const int wave = threadIdx.x >> 6;
    const int lane = threadIdx.x & 63;

    // gate: 512-length dot, 8 FMA per lane, butterfly so every lane has it
    const float* yb = y + b * C;
    const float* wm = W + m * C;
    float s = 0.f;
    #pragma unroll
    for (int i = 0; i < 8; ++i) s = fmaf(yb[lane + 64 * i], wm[lane + 64 * i], s);
    #pragma unroll
    for (int off = 32; off; off >>= 1) s += __shfl_xor(s, off, 64);
    s += bias[m];
    s = fmaxf(s, 0.f);                         // relu
    const float g = 1.0f / (1.0f + expf(-s));  // sigmoid

    const int row = row0 + wave;
    const floatx4* xr  = reinterpret_cast<const floatx4*>(x) + (size_t)row * HW4;
    floatx4*      orow = reinterpret_cast<floatx4*>(out)     + (size_t)row * HW4;
    for (int i = lane; i < HW4; i += 64) {
        floatx4 v = xr[i];
        v *= g;
        __builtin_nontemporal_store(v, &orow[i]);   // nt: don't pollute L2/L3
    }
}

extern "C" void kernel_launch(void* const* d_in, const int* in_sizes, int n_in,
                              void* d_out, int out_size, void* d_ws, size_t ws_size,
                              hipStream_t stream) {
    const float* x    = (const float*)d_in[0];  // (32,512,56,56)
    const float* W    = (const float*)d_in[1];  // (8,512)
    const float* bias = (const float*)d_in[2];  // (8,)
    float* out = (float*)d_out;

    float* y = (float*)d_ws;                    // 16384 floats = 64 KB

    se_mean_kernel<<<ROWS / 4, 256, 0, stream>>>(x, y);
    se_scale_kernel<<<ROWS / 4, 256, 0, stream>>>(x, y, W, bias, out);
}